// Round 8
// baseline (11403.445 us; speedup 1.0000x reference)
//
#include <hip/hip_runtime.h>
#include <hip/hip_bf16.h>
#include <cstdint>
#include <cstddef>

#define HID 512
#define N_INT 131072
#define N_INIT 32768

typedef __attribute__((ext_vector_type(8))) short short8_t;
typedef __attribute__((ext_vector_type(4))) float floatx4;

__device__ __forceinline__ float bf2f(unsigned short u) {
  return __uint_as_float(((unsigned)u) << 16);
}
__device__ __forceinline__ unsigned short f2bf_rne(float x) {
  unsigned u = __float_as_uint(x);
  unsigned r = u + 0x7FFF + ((u >> 16) & 1);
  return (unsigned short)(r >> 16);
}
__device__ __forceinline__ void st_split(unsigned short* hi, unsigned short* lo,
                                         size_t off, float x) {
  unsigned short h = f2bf_rne(x);
  hi[off] = h;
  lo[off] = f2bf_rne(x - bf2f(h));
}
__device__ __forceinline__ void gl_lds16(const unsigned short* g, unsigned short* l) {
  __builtin_amdgcn_global_load_lds(
      (const __attribute__((address_space(1))) unsigned int*)g,
      (__attribute__((address_space(3))) unsigned int*)l, 16, 0, 0);
}

// fraglet offset for element (row, col) in a [rows][512] matrix stored as
// MFMA-operand fraglets: fraglet (row>>4, col>>5); lane = ((col>>3)&3)*16
// + (row&15); elem = col&7.  One fraglet = 1KB contiguous.
__device__ __forceinline__ size_t foff(int row, int col) {
  return (size_t)(row >> 4) * 8192 + (size_t)(col >> 5) * 512 +
         (size_t)(((col >> 3) & 3) * 128) + (size_t)((row & 15) << 3) +
         (size_t)(col & 7);
}

// ---------------------------------------------------------------------------
// Layer 0 (2 -> 512), closed-form tangents; vectorized: 8 cols/thread, one
// aligned short8 (16B) store per plane. Block = 512 thr = 8 rows x 64 colblk.
// ---------------------------------------------------------------------------
__global__ __launch_bounds__(512) void layer0_int(
    const float* __restrict__ xt, long row0, int rows,
    const float* __restrict__ W0, const float* __restrict__ b0,
    unsigned short* __restrict__ act, size_t P)
{
  const int lr = threadIdx.x >> 6;
  const int cb = threadIdx.x & 63;
  const long i = (long)blockIdx.x * 8 + lr;
  if (i >= rows) return;
  const float x = xt[(row0 + i) * 2 + 0];
  const float t = xt[(row0 + i) * 2 + 1];
  const int j0 = cb << 3;
  const float4 wxa = *(const float4*)(W0 + j0);
  const float4 wxb = *(const float4*)(W0 + j0 + 4);
  const float4 wta = *(const float4*)(W0 + HID + j0);
  const float4 wtb = *(const float4*)(W0 + HID + j0 + 4);
  const float4 ba = *(const float4*)(b0 + j0);
  const float4 bb = *(const float4*)(b0 + j0 + 4);
  const float wxv[8] = {wxa.x, wxa.y, wxa.z, wxa.w, wxb.x, wxb.y, wxb.z, wxb.w};
  const float wtv[8] = {wta.x, wta.y, wta.z, wta.w, wtb.x, wtb.y, wtb.z, wtb.w};
  const float bv[8]  = {ba.x, ba.y, ba.z, ba.w, bb.x, bb.y, bb.z, bb.w};
  short8_t h[5], l[5];
#pragma unroll
  for (int jj = 0; jj < 8; ++jj) {
    const float wx = wxv[jj], wt = wtv[jj];
    const float a = fmaf(x, wx, fmaf(t, wt, bv[jj]));
    const float y = tanhf(a);
    const float d = 1.f - y * y;
    const float vals[5] = {y, d * wt, -2.f * y * d * wt * wt,
                           d * wx, -2.f * y * d * wx * wx};
#pragma unroll
    for (int p = 0; p < 5; ++p) {
      const unsigned short hv = f2bf_rne(vals[p]);
      h[p][jj] = (short)hv;
      l[p][jj] = (short)f2bf_rne(vals[p] - bf2f(hv));
    }
  }
  const size_t base = foff((int)i, j0);
#pragma unroll
  for (int p = 0; p < 5; ++p) {
    *(short8_t*)(act + (size_t)(2 * p) * P + base) = h[p];
    *(short8_t*)(act + (size_t)(2 * p + 1) * P + base) = l[p];
  }
}

__global__ __launch_bounds__(512) void layer0_init(
    const float* __restrict__ xt, long row0, int rows,
    const float* __restrict__ W0, const float* __restrict__ b0,
    unsigned short* __restrict__ act, size_t P)
{
  const int lr = threadIdx.x >> 6;
  const int cb = threadIdx.x & 63;
  const long i = (long)blockIdx.x * 8 + lr;
  if (i >= rows) return;
  const float x = xt[(row0 + i) * 2 + 0];
  const float t = xt[(row0 + i) * 2 + 1];
  const int j0 = cb << 3;
  const float4 wxa = *(const float4*)(W0 + j0);
  const float4 wxb = *(const float4*)(W0 + j0 + 4);
  const float4 wta = *(const float4*)(W0 + HID + j0);
  const float4 wtb = *(const float4*)(W0 + HID + j0 + 4);
  const float4 ba = *(const float4*)(b0 + j0);
  const float4 bb = *(const float4*)(b0 + j0 + 4);
  const float wxv[8] = {wxa.x, wxa.y, wxa.z, wxa.w, wxb.x, wxb.y, wxb.z, wxb.w};
  const float wtv[8] = {wta.x, wta.y, wta.z, wta.w, wtb.x, wtb.y, wtb.z, wtb.w};
  const float bv[8]  = {ba.x, ba.y, ba.z, ba.w, bb.x, bb.y, bb.z, bb.w};
  short8_t h[2], l[2];
#pragma unroll
  for (int jj = 0; jj < 8; ++jj) {
    const float wx = wxv[jj], wt = wtv[jj];
    const float a = fmaf(x, wx, fmaf(t, wt, bv[jj]));
    const float y = tanhf(a);
    const float d = 1.f - y * y;
    const float vals[2] = {y, d * wt};
#pragma unroll
    for (int p = 0; p < 2; ++p) {
      const unsigned short hv = f2bf_rne(vals[p]);
      h[p][jj] = (short)hv;
      l[p][jj] = (short)f2bf_rne(vals[p] - bf2f(hv));
    }
  }
  const size_t base = foff((int)i, j0);
#pragma unroll
  for (int p = 0; p < 2; ++p) {
    *(short8_t*)(act + (size_t)(2 * p) * P + base) = h[p];
    *(short8_t*)(act + (size_t)(2 * p + 1) * P + base) = l[p];
  }
}

// ---------------------------------------------------------------------------
// W split + pack into B-fraglet layout (n -> fraglet row role):
//   fraglet (n>>4, k>>5); lane = ((k>>3)&3)*16 + (n&15); elem = k&7.
// ---------------------------------------------------------------------------
__global__ __launch_bounds__(512) void wsplit(
    const float* __restrict__ W,
    unsigned short* __restrict__ WfH, unsigned short* __restrict__ WfL)
{
  int n = blockIdx.x;
  int k = threadIdx.x;
  float w = W[(size_t)k * HID + n];
  size_t o = ((((size_t)(n >> 4) * 16 + (k >> 5)) * 64
               + ((k >> 3) & 3) * 16 + (n & 15)) << 3) + (k & 7);
  st_split(WfH, WfL, o, w);
}

// ---------------------------------------------------------------------------
// Fused NS-stream split-bf16 MFMA GEMM.
// 256 thr = 4 waves (1m x 4n); block tile 32x128; wave tile 32x32 per stream.
// A: staged to LDS as fraglets (global_load_lds, linear both sides), dbuf,
//    shared by all 4 waves. B: register-double-buffered fraglet loads (L2).
// 4 blocks/CU (LDS 40KB, VGPR<=128): independent per-block barriers stagger,
// so one block's MFMA burst covers another's vmcnt/barrier drain.
// s_setprio(1) around the MFMA cluster (independent-block regime).
// C = Ah@Wh + Ah@Wl + Al@Wh (fp32 accum) per stream, W shared across streams.
// ---------------------------------------------------------------------------
template <int NS, bool LAST>
__global__ __launch_bounds__(256, 4) void gemm_mfma(
    const unsigned short* __restrict__ inp,   // 2*NS fraglet planes of P elems
    const unsigned short* __restrict__ WfH,   // fraglet-packed 512x512
    const unsigned short* __restrict__ WfL,
    const float* __restrict__ bias,
    unsigned short* __restrict__ outp,        // 2*NS fraglet planes (!LAST)
    float* __restrict__ outf,                 // 2 f32 planes (LAST)
    size_t P, int nwg)
{
  __shared__ unsigned short Asm[2][NS * 4 * 512];  // per k-step: NS*4 fraglets

  const int bid = blockIdx.x;
  // XCD-grouped order (nwg multiple of 8): the 4 n-blocks of an m-panel are
  // consecutive logical ids -> same XCD -> A panel re-reads hit that L2/L3.
  const int o = (bid & 7) * (nwg >> 3) + (bid >> 3);
  const long bm = (long)(o >> 2) << 5;
  const int bn = (o & 3) << 7;

  const int lane = threadIdx.x & 63;
  const int wv = threadIdx.x >> 6;   // 0..3 = n-quarter

  floatx4 acc[NS][2][2];             // [stream][rf(m16)][cf(n16)]
#pragma unroll
  for (int s = 0; s < NS; ++s)
#pragma unroll
    for (int rf = 0; rf < 2; ++rf)
#pragma unroll
      for (int cf = 0; cf < 2; ++cf)
#pragma unroll
        for (int e = 0; e < 4; ++e) acc[s][rf][cf][e] = 0.f;

  const int mt0 = (int)(bm >> 4);

  // ---- A staging: NS*4 fraglets per k-step, NS per wave.
  // fraglet id f = s*4 + mt*2 + p  (mt: m-tile within block, p: hi/lo)
  const unsigned short* asrc[NS];
  unsigned adst[NS];
#pragma unroll
  for (int u = 0; u < NS; ++u) {
    const int f = wv * NS + u;
    const int s = f >> 2, mtl = (f >> 1) & 1, p = f & 1;
    asrc[u] = inp + (size_t)(2 * s + p) * P + (size_t)(mt0 + mtl) * 8192 + (lane << 3);
    adst[u] = (unsigned)f * 512;
  }

  // ---- B fraglet pointers (16B/lane coalesced); this wave's 2 n-tiles
  const int bnt = (bn >> 4) + wv * 2;
  const unsigned short* bbh = WfH + ((size_t)bnt << 13) + (lane << 3);
  const unsigned short* bbl = WfL + ((size_t)bnt << 13) + (lane << 3);

  short8_t bh[2][2], bl[2][2];  // [k-parity][cf]

  // ---- prologue: stage A(0), load B(0)
#pragma unroll
  for (int u = 0; u < NS; ++u)
    gl_lds16(asrc[u], &Asm[0][adst[u]]);
#pragma unroll
  for (int cf = 0; cf < 2; ++cf) {
    bh[0][cf] = *(const short8_t*)(bbh + ((size_t)cf << 13));
    bl[0][cf] = *(const short8_t*)(bbl + ((size_t)cf << 13));
  }
  asm volatile("s_waitcnt vmcnt(0)" ::: "memory");
  __builtin_amdgcn_s_barrier();

#pragma unroll
  for (int t = 0; t < 16; ++t) {
    const int cur = t & 1;
    if (t < 15) {
      // issue next tile's A staging + B register prefetch (in flight during MFMA)
#pragma unroll
      for (int u = 0; u < NS; ++u)
        gl_lds16(asrc[u] + ((t + 1) << 9), &Asm[cur ^ 1][adst[u]]);
#pragma unroll
      for (int cf = 0; cf < 2; ++cf) {
        bh[cur ^ 1][cf] = *(const short8_t*)(bbh + ((size_t)cf << 13) + ((t + 1) << 9));
        bl[cur ^ 1][cf] = *(const short8_t*)(bbl + ((size_t)cf << 13) + ((t + 1) << 9));
      }
      asm volatile("" ::: "memory");  // keep prefetch issue ahead of compute
    }
    // compute k-tile t: A frags from LDS (linear, conflict-free), B from regs
    __builtin_amdgcn_s_setprio(1);
#pragma unroll
    for (int s = 0; s < NS; ++s) {
      const unsigned short* As = &Asm[cur][(unsigned)s * 2048 + (lane << 3)];
      const short8_t ah0 = *(const short8_t*)(As);
      const short8_t al0 = *(const short8_t*)(As + 512);
      const short8_t ah1 = *(const short8_t*)(As + 1024);
      const short8_t al1 = *(const short8_t*)(As + 1536);
#pragma unroll
      for (int cf = 0; cf < 2; ++cf) {
        acc[s][0][cf] = __builtin_amdgcn_mfma_f32_16x16x32_bf16(ah0, bh[cur][cf], acc[s][0][cf], 0, 0, 0);
        acc[s][0][cf] = __builtin_amdgcn_mfma_f32_16x16x32_bf16(ah0, bl[cur][cf], acc[s][0][cf], 0, 0, 0);
        acc[s][0][cf] = __builtin_amdgcn_mfma_f32_16x16x32_bf16(al0, bh[cur][cf], acc[s][0][cf], 0, 0, 0);
        acc[s][1][cf] = __builtin_amdgcn_mfma_f32_16x16x32_bf16(ah1, bh[cur][cf], acc[s][1][cf], 0, 0, 0);
        acc[s][1][cf] = __builtin_amdgcn_mfma_f32_16x16x32_bf16(ah1, bl[cur][cf], acc[s][1][cf], 0, 0, 0);
        acc[s][1][cf] = __builtin_amdgcn_mfma_f32_16x16x32_bf16(al1, bh[cur][cf], acc[s][1][cf], 0, 0, 0);
      }
    }
    __builtin_amdgcn_s_setprio(0);
    if (t < 15) {
      asm volatile("s_waitcnt vmcnt(0)" ::: "memory");  // A(t+1)+B(t+1) landed
      __builtin_amdgcn_s_barrier();
    }
  }

  // ---- epilogue: tanh coupling
  const int frow = lane & 15;
  const int fq = lane >> 4;
#pragma unroll
  for (int rf = 0; rf < 2; ++rf) {
#pragma unroll
    for (int cf = 0; cf < 2; ++cf) {
      const int col = bn + wv * 32 + cf * 16 + frow;
      const float bv = bias[col];
      const size_t fbase = (size_t)(mt0 + rf) * 8192 + (size_t)(col >> 5) * 512 +
                           (size_t)(((col >> 3) & 3) * 128) + (size_t)(col & 7);
#pragma unroll
      for (int j = 0; j < 4; ++j) {
        const float a0 = acc[0][rf][cf][j] + bv;
        const float e = __expf(2.f * a0);
        const float y = 1.f - __fdividef(2.f, e + 1.f);
        const float d = 1.f - y * y;
        const float a1 = acc[1][rf][cf][j];
        const float o1 = d * a1;
        if (LAST) {
          const size_t row = (size_t)(bm + rf * 16 + fq * 4 + j);
          const size_t off = (row << 9) + col;
          if (NS == 5) {
            const float a2 = acc[2][rf][cf][j];
            const float a3 = acc[3][rf][cf][j];
            const float a4 = acc[4][rf][cf][j];
            const float o2 = fmaf(-2.f * y * a1, o1, d * a2);
            const float o3 = d * a3;
            const float o4 = fmaf(-2.f * y * a3, o3, d * a4);
            outf[off] = o2;        // u_tt'' activation
            outf[P + off] = o4;    // u_xx'' activation
          } else {
            outf[off] = y;         // h activation
            outf[P + off] = o1;    // u_t' activation
          }
        } else {
          const size_t off = fbase + (size_t)((fq * 4 + j) << 3);
          st_split(outp + 0 * P, outp + 1 * P, off, y);
          st_split(outp + 2 * P, outp + 3 * P, off, o1);
          if (NS == 5) {
            const float a2 = acc[2][rf][cf][j];
            const float a3 = acc[3][rf][cf][j];
            const float a4 = acc[4][rf][cf][j];
            const float o2 = fmaf(-2.f * y * a1, o1, d * a2);
            const float o3 = d * a3;
            const float o4 = fmaf(-2.f * y * a3, o3, d * a4);
            st_split(outp + 4 * P, outp + 5 * P, off, o2);
            st_split(outp + 6 * P, outp + 7 * P, off, o3);
            st_split(outp + 8 * P, outp + 9 * P, off, o4);
          }
        }
      }
    }
  }
}

// ---------------------------------------------------------------------------
// Final layer (512 -> 1) dots + loss accumulation, f32 row-major inputs.
// ---------------------------------------------------------------------------
__global__ __launch_bounds__(256) void final_int(
    const float* __restrict__ uf, size_t P,
    const float* __restrict__ W4, const float* __restrict__ f,
    const float* __restrict__ c, float* __restrict__ out,
    int rows, float scale)
{
  __shared__ float ls[4];
  int lane = threadIdx.x & 63, w = threadIdx.x >> 6;
  long i = (long)blockIdx.x * 4 + w;
  float val = 0.f;
  if (i < rows) {
    const float* ut = uf + (i << 9) + (lane << 3);
    const float* ux = ut + P;
    float s_t = 0.f, s_x = 0.f;
#pragma unroll
    for (int j = 0; j < 8; ++j) {
      float wv4 = W4[(lane << 3) + j];
      s_t = fmaf(ut[j], wv4, s_t);
      s_x = fmaf(ux[j], wv4, s_x);
    }
#pragma unroll
    for (int off = 32; off; off >>= 1) {
      s_t += __shfl_xor(s_t, off);
      s_x += __shfl_xor(s_x, off);
    }
    if (lane == 0) {
      float c0 = c[0];
      float pred = s_t - c0 * c0 * s_x;
      float r = pred - f[i];
      val = r * r;
    }
  }
  if (lane == 0) ls[w] = val;
  __syncthreads();
  if (threadIdx.x == 0)
    atomicAdd(out + 2, scale * (ls[0] + ls[1] + ls[2] + ls[3]));
}

__global__ __launch_bounds__(256) void final_init(
    const float* __restrict__ uf, size_t P,
    const float* __restrict__ W4, const float* __restrict__ b4,
    const float* __restrict__ g, const float* __restrict__ gd,
    float* __restrict__ out, int rows, float scale)
{
  __shared__ float ls0[4], ls1[4];
  int lane = threadIdx.x & 63, w = threadIdx.x >> 6;
  long i = (long)blockIdx.x * 4 + w;
  float v0 = 0.f, v1 = 0.f;
  if (i < rows) {
    const float* h = uf + (i << 9) + (lane << 3);
    const float* tt = h + P;
    float su = 0.f, stt = 0.f;
#pragma unroll
    for (int j = 0; j < 8; ++j) {
      float wv4 = W4[(lane << 3) + j];
      su = fmaf(h[j], wv4, su);
      stt = fmaf(tt[j], wv4, stt);
    }
#pragma unroll
    for (int off = 32; off; off >>= 1) {
      su += __shfl_xor(su, off);
      stt += __shfl_xor(stt, off);
    }
    if (lane == 0) {
      float r0 = su + b4[0] - g[i];
      float r1 = stt - gd[i];
      v0 = r0 * r0;
      v1 = r1 * r1;
    }
  }
  if (lane == 0) { ls0[w] = v0; ls1[w] = v1; }
  __syncthreads();
  if (threadIdx.x == 0) {
    atomicAdd(out + 0, scale * (ls0[0] + ls0[1] + ls0[2] + ls0[3]));
    atomicAdd(out + 1, scale * (ls1[0] + ls1[1] + ls1[2] + ls1[3]));
  }
}

// ---------------------------------------------------------------------------
extern "C" void kernel_launch(void* const* d_in, const int* in_sizes, int n_in,
                              void* d_out, int out_size, void* d_ws, size_t ws_size,
                              hipStream_t stream)
{
  const float* xt_int  = (const float*)d_in[0];
  const float* f       = (const float*)d_in[1];
  const float* xt_init = (const float*)d_in[2];
  const float* g       = (const float*)d_in[3];
  const float* gd      = (const float*)d_in[4];
  const float* W0 = (const float*)d_in[5];
  const float* b0 = (const float*)d_in[6];
  const float* W1 = (const float*)d_in[7];
  const float* b1 = (const float*)d_in[8];
  const float* W2 = (const float*)d_in[9];
  const float* b2 = (const float*)d_in[10];
  const float* W3 = (const float*)d_in[11];
  const float* b3 = (const float*)d_in[12];
  const float* W4 = (const float*)d_in[13];
  const float* b4 = (const float*)d_in[14];
  const float* c  = (const float*)d_in[15];
  float* out = (float*)d_out;

  hipMemsetAsync(out, 0, 3 * sizeof(float), stream);

  unsigned short* wsp = (unsigned short*)d_ws;
  const size_t WT1 = (size_t)HID * HID;     // one 512x512 plane (elems)
  const size_t wtotal = 6 * WT1;            // 3 layers x {hi,lo}
  unsigned short* Wt = wsp;

  // per-row cost: 2 bf16 buffers x 10 planes x 512 + 1 f32 buffer x 2 planes
  const size_t row_bytes = 2 * 10 * HID * 2 + 2 * HID * 4;  // 24576
  long maxRc = (long)((ws_size - wtotal * 2) / row_bytes);
  long Rc = 128;
  while (Rc * 2 <= maxRc && Rc < 8192) Rc <<= 1;
  size_t P = (size_t)Rc * HID;
  unsigned short* bufA = wsp + wtotal;
  unsigned short* bufB = bufA + 10 * P;
  float* fbuf = (float*)(bufB + 10 * P);

  wsplit<<<HID, HID, 0, stream>>>(W1, Wt + 0 * WT1, Wt + 1 * WT1);
  wsplit<<<HID, HID, 0, stream>>>(W2, Wt + 2 * WT1, Wt + 3 * WT1);
  wsplit<<<HID, HID, 0, stream>>>(W3, Wt + 4 * WT1, Wt + 5 * WT1);

  const float sc_f = 0.5f / (float)N_INT;
  const float sc_i = 0.5f / (float)N_INIT;

  // ---- interior pass (5 streams) ----
  for (long i0 = 0; i0 < N_INT; i0 += Rc) {
    long rem = N_INT - i0;
    int rows = (int)(rem < Rc ? rem : Rc);
    layer0_int<<<(rows + 7) / 8, 512, 0, stream>>>(xt_int, i0, rows, W0, b0, bufA, P);
    int nwg = (rows / 32) * 4;
    gemm_mfma<5, false><<<nwg, 256, 0, stream>>>(bufA, Wt + 0 * WT1, Wt + 1 * WT1, b1, bufB, nullptr, P, nwg);
    gemm_mfma<5, false><<<nwg, 256, 0, stream>>>(bufB, Wt + 2 * WT1, Wt + 3 * WT1, b2, bufA, nullptr, P, nwg);
    gemm_mfma<5, true><<<nwg, 256, 0, stream>>>(bufA, Wt + 4 * WT1, Wt + 5 * WT1, b3, nullptr, fbuf, P, nwg);
    final_int<<<(rows + 3) / 4, 256, 0, stream>>>(fbuf, P, W4, f + i0, c, out, rows, sc_f);
  }

  // ---- init pass (2 streams) ----
  for (long i0 = 0; i0 < N_INIT; i0 += Rc) {
    long rem = N_INIT - i0;
    int rows = (int)(rem < Rc ? rem : Rc);
    layer0_init<<<(rows + 7) / 8, 512, 0, stream>>>(xt_init, i0, rows, W0, b0, bufA, P);
    int nwg = (rows / 32) * 4;
    gemm_mfma<2, false><<<nwg, 256, 0, stream>>>(bufA, Wt + 0 * WT1, Wt + 1 * WT1, b1, bufB, nullptr, P, nwg);
    gemm_mfma<2, false><<<nwg, 256, 0, stream>>>(bufB, Wt + 2 * WT1, Wt + 3 * WT1, b2, bufA, nullptr, P, nwg);
    gemm_mfma<2, true><<<nwg, 256, 0, stream>>>(bufA, Wt + 4 * WT1, Wt + 5 * WT1, b3, nullptr, fbuf, P, nwg);
    final_init<<<(rows + 3) / 4, 256, 0, stream>>>(fbuf, P, W4, b4, g + i0, gd + i0, out, rows, sc_i);
  }
}

// Round 9
// 6920.363 us; speedup vs baseline: 1.6478x; 1.6478x over previous
//
#include <hip/hip_runtime.h>
#include <hip/hip_bf16.h>
#include <cstdint>
#include <cstddef>

#define HID 512
#define N_INT 131072
#define N_INIT 32768

typedef __attribute__((ext_vector_type(8))) short short8_t;
typedef __attribute__((ext_vector_type(4))) float floatx4;

__device__ __forceinline__ float bf2f(unsigned short u) {
  return __uint_as_float(((unsigned)u) << 16);
}
__device__ __forceinline__ unsigned short f2bf_rne(float x) {
  unsigned u = __float_as_uint(x);
  unsigned r = u + 0x7FFF + ((u >> 16) & 1);
  return (unsigned short)(r >> 16);
}
__device__ __forceinline__ void st_split(unsigned short* hi, unsigned short* lo,
                                         size_t off, float x) {
  unsigned short h = f2bf_rne(x);
  hi[off] = h;
  lo[off] = f2bf_rne(x - bf2f(h));
}
__device__ __forceinline__ void gl_lds16(const unsigned short* g, unsigned short* l) {
  __builtin_amdgcn_global_load_lds(
      (const __attribute__((address_space(1))) unsigned int*)g,
      (__attribute__((address_space(3))) unsigned int*)l, 16, 0, 0);
}

// fraglet offset for element (row, col) in a [rows][512] matrix stored as
// MFMA-operand fraglets: fraglet (row>>4, col>>5); lane = ((col>>3)&3)*16
// + (row&15); elem = col&7.  One fraglet = 1KB contiguous.
__device__ __forceinline__ size_t foff(int row, int col) {
  return (size_t)(row >> 4) * 8192 + (size_t)(col >> 5) * 512 +
         (size_t)(((col >> 3) & 3) * 128) + (size_t)((row & 15) << 3) +
         (size_t)(col & 7);
}

// ---------------------------------------------------------------------------
// Layer 0 (2 -> 512), closed-form tangents; vectorized: 8 cols/thread, one
// aligned short8 (16B) store per plane. Block = 512 thr = 8 rows x 64 colblk.
// ---------------------------------------------------------------------------
__global__ __launch_bounds__(512) void layer0_int(
    const float* __restrict__ xt, long row0, int rows,
    const float* __restrict__ W0, const float* __restrict__ b0,
    unsigned short* __restrict__ act, size_t P)
{
  const int lr = threadIdx.x >> 6;
  const int cb = threadIdx.x & 63;
  const long i = (long)blockIdx.x * 8 + lr;
  if (i >= rows) return;
  const float x = xt[(row0 + i) * 2 + 0];
  const float t = xt[(row0 + i) * 2 + 1];
  const int j0 = cb << 3;
  const float4 wxa = *(const float4*)(W0 + j0);
  const float4 wxb = *(const float4*)(W0 + j0 + 4);
  const float4 wta = *(const float4*)(W0 + HID + j0);
  const float4 wtb = *(const float4*)(W0 + HID + j0 + 4);
  const float4 ba = *(const float4*)(b0 + j0);
  const float4 bb = *(const float4*)(b0 + j0 + 4);
  const float wxv[8] = {wxa.x, wxa.y, wxa.z, wxa.w, wxb.x, wxb.y, wxb.z, wxb.w};
  const float wtv[8] = {wta.x, wta.y, wta.z, wta.w, wtb.x, wtb.y, wtb.z, wtb.w};
  const float bv[8]  = {ba.x, ba.y, ba.z, ba.w, bb.x, bb.y, bb.z, bb.w};
  short8_t h[5], l[5];
#pragma unroll
  for (int jj = 0; jj < 8; ++jj) {
    const float wx = wxv[jj], wt = wtv[jj];
    const float a = fmaf(x, wx, fmaf(t, wt, bv[jj]));
    const float y = tanhf(a);
    const float d = 1.f - y * y;
    const float vals[5] = {y, d * wt, -2.f * y * d * wt * wt,
                           d * wx, -2.f * y * d * wx * wx};
#pragma unroll
    for (int p = 0; p < 5; ++p) {
      const unsigned short hv = f2bf_rne(vals[p]);
      h[p][jj] = (short)hv;
      l[p][jj] = (short)f2bf_rne(vals[p] - bf2f(hv));
    }
  }
  const size_t base = foff((int)i, j0);
#pragma unroll
  for (int p = 0; p < 5; ++p) {
    *(short8_t*)(act + (size_t)(2 * p) * P + base) = h[p];
    *(short8_t*)(act + (size_t)(2 * p + 1) * P + base) = l[p];
  }
}

__global__ __launch_bounds__(512) void layer0_init(
    const float* __restrict__ xt, long row0, int rows,
    const float* __restrict__ W0, const float* __restrict__ b0,
    unsigned short* __restrict__ act, size_t P)
{
  const int lr = threadIdx.x >> 6;
  const int cb = threadIdx.x & 63;
  const long i = (long)blockIdx.x * 8 + lr;
  if (i >= rows) return;
  const float x = xt[(row0 + i) * 2 + 0];
  const float t = xt[(row0 + i) * 2 + 1];
  const int j0 = cb << 3;
  const float4 wxa = *(const float4*)(W0 + j0);
  const float4 wxb = *(const float4*)(W0 + j0 + 4);
  const float4 wta = *(const float4*)(W0 + HID + j0);
  const float4 wtb = *(const float4*)(W0 + HID + j0 + 4);
  const float4 ba = *(const float4*)(b0 + j0);
  const float4 bb = *(const float4*)(b0 + j0 + 4);
  const float wxv[8] = {wxa.x, wxa.y, wxa.z, wxa.w, wxb.x, wxb.y, wxb.z, wxb.w};
  const float wtv[8] = {wta.x, wta.y, wta.z, wta.w, wtb.x, wtb.y, wtb.z, wtb.w};
  const float bv[8]  = {ba.x, ba.y, ba.z, ba.w, bb.x, bb.y, bb.z, bb.w};
  short8_t h[2], l[2];
#pragma unroll
  for (int jj = 0; jj < 8; ++jj) {
    const float wx = wxv[jj], wt = wtv[jj];
    const float a = fmaf(x, wx, fmaf(t, wt, bv[jj]));
    const float y = tanhf(a);
    const float d = 1.f - y * y;
    const float vals[2] = {y, d * wt};
#pragma unroll
    for (int p = 0; p < 2; ++p) {
      const unsigned short hv = f2bf_rne(vals[p]);
      h[p][jj] = (short)hv;
      l[p][jj] = (short)f2bf_rne(vals[p] - bf2f(hv));
    }
  }
  const size_t base = foff((int)i, j0);
#pragma unroll
  for (int p = 0; p < 2; ++p) {
    *(short8_t*)(act + (size_t)(2 * p) * P + base) = h[p];
    *(short8_t*)(act + (size_t)(2 * p + 1) * P + base) = l[p];
  }
}

// ---------------------------------------------------------------------------
// W split + pack into B-fraglet layout (n -> fraglet row role):
//   fraglet (n>>4, k>>5); lane = ((k>>3)&3)*16 + (n&15); elem = k&7.
// ---------------------------------------------------------------------------
__global__ __launch_bounds__(512) void wsplit(
    const float* __restrict__ W,
    unsigned short* __restrict__ WfH, unsigned short* __restrict__ WfL)
{
  int n = blockIdx.x;
  int k = threadIdx.x;
  float w = W[(size_t)k * HID + n];
  size_t o = ((((size_t)(n >> 4) * 16 + (k >> 5)) * 64
               + ((k >> 3) & 3) * 16 + (n & 15)) << 3) + (k & 7);
  st_split(WfH, WfL, o, w);
}

// ---------------------------------------------------------------------------
// Fused NS-stream split-bf16 MFMA GEMM.
// 256 thr = 4 waves (1m x 4n); block tile 32x128; wave tile 32x32 per stream.
// A: staged to LDS as fraglets (global_load_lds, linear both sides), dbuf,
//    shared by all 4 waves. B: register-double-buffered fraglet loads (L2).
// Rc=2048 chunking keeps ping-pong activation buffers ~2.6MB/XCD so the
// producer layer's writes are consumed from the same XCD's L2 (the swizzle
// maps panel p to the same XCD in every dispatch with equal nwg).
// Pipeline: stage(t+1)+B(t+1) issued before the MFMA burst; burst covers L2
// latency; raw s_barrier + explicit vmcnt(0).
// C = Ah@Wh + Ah@Wl + Al@Wh (fp32 accum) per stream, W shared across streams.
// ---------------------------------------------------------------------------
template <int NS, bool LAST>
__global__ __launch_bounds__(256, 2) void gemm_mfma(
    const unsigned short* __restrict__ inp,   // 2*NS fraglet planes of P elems
    const unsigned short* __restrict__ WfH,   // fraglet-packed 512x512
    const unsigned short* __restrict__ WfL,
    const float* __restrict__ bias,
    unsigned short* __restrict__ outp,        // 2*NS fraglet planes (!LAST)
    float* __restrict__ outf,                 // 2 f32 planes (LAST)
    size_t P, int nwg)
{
  __shared__ unsigned short Asm[2][NS * 4 * 512];  // per k-step: NS*4 fraglets

  const int bid = blockIdx.x;
  // XCD-grouped order (nwg multiple of 8): the 4 n-blocks of an m-panel are
  // consecutive logical ids -> same XCD -> producer/consumer L2 locality.
  const int o = (bid & 7) * (nwg >> 3) + (bid >> 3);
  const long bm = (long)(o >> 2) << 5;
  const int bn = (o & 3) << 7;

  const int lane = threadIdx.x & 63;
  const int wv = threadIdx.x >> 6;   // 0..3 = n-quarter

  floatx4 acc[NS][2][2];             // [stream][rf(m16)][cf(n16)]
#pragma unroll
  for (int s = 0; s < NS; ++s)
#pragma unroll
    for (int rf = 0; rf < 2; ++rf)
#pragma unroll
      for (int cf = 0; cf < 2; ++cf)
#pragma unroll
        for (int e = 0; e < 4; ++e) acc[s][rf][cf][e] = 0.f;

  const int mt0 = (int)(bm >> 4);

  // ---- A staging: NS*4 fraglets per k-step, NS per wave.
  // fraglet id f = s*4 + mt*2 + p  (mt: m-tile within block, p: hi/lo)
  const unsigned short* asrc[NS];
  unsigned adst[NS];
#pragma unroll
  for (int u = 0; u < NS; ++u) {
    const int f = wv * NS + u;
    const int s = f >> 2, mtl = (f >> 1) & 1, p = f & 1;
    asrc[u] = inp + (size_t)(2 * s + p) * P + (size_t)(mt0 + mtl) * 8192 + (lane << 3);
    adst[u] = (unsigned)f * 512;
  }

  // ---- B fraglet pointers (16B/lane coalesced); this wave's 2 n-tiles
  const int bnt = (bn >> 4) + wv * 2;
  const unsigned short* bbh = WfH + ((size_t)bnt << 13) + (lane << 3);
  const unsigned short* bbl = WfL + ((size_t)bnt << 13) + (lane << 3);

  short8_t bh[2][2], bl[2][2];  // [k-parity][cf]

  // ---- prologue: stage A(0), load B(0)
#pragma unroll
  for (int u = 0; u < NS; ++u)
    gl_lds16(asrc[u], &Asm[0][adst[u]]);
#pragma unroll
  for (int cf = 0; cf < 2; ++cf) {
    bh[0][cf] = *(const short8_t*)(bbh + ((size_t)cf << 13));
    bl[0][cf] = *(const short8_t*)(bbl + ((size_t)cf << 13));
  }
  asm volatile("s_waitcnt vmcnt(0)" ::: "memory");
  __builtin_amdgcn_s_barrier();

#pragma unroll
  for (int t = 0; t < 16; ++t) {
    const int cur = t & 1;
    if (t < 15) {
      // issue next tile's A staging + B register prefetch (in flight during MFMA)
#pragma unroll
      for (int u = 0; u < NS; ++u)
        gl_lds16(asrc[u] + ((t + 1) << 9), &Asm[cur ^ 1][adst[u]]);
#pragma unroll
      for (int cf = 0; cf < 2; ++cf) {
        bh[cur ^ 1][cf] = *(const short8_t*)(bbh + ((size_t)cf << 13) + ((t + 1) << 9));
        bl[cur ^ 1][cf] = *(const short8_t*)(bbl + ((size_t)cf << 13) + ((t + 1) << 9));
      }
      asm volatile("" ::: "memory");  // keep prefetch issue ahead of compute
    }
    // compute k-tile t: A frags from LDS (linear, conflict-free), B from regs
    __builtin_amdgcn_s_setprio(1);
#pragma unroll
    for (int s = 0; s < NS; ++s) {
      const unsigned short* As = &Asm[cur][(unsigned)s * 2048 + (lane << 3)];
      const short8_t ah0 = *(const short8_t*)(As);
      const short8_t al0 = *(const short8_t*)(As + 512);
      const short8_t ah1 = *(const short8_t*)(As + 1024);
      const short8_t al1 = *(const short8_t*)(As + 1536);
#pragma unroll
      for (int cf = 0; cf < 2; ++cf) {
        acc[s][0][cf] = __builtin_amdgcn_mfma_f32_16x16x32_bf16(ah0, bh[cur][cf], acc[s][0][cf], 0, 0, 0);
        acc[s][0][cf] = __builtin_amdgcn_mfma_f32_16x16x32_bf16(ah0, bl[cur][cf], acc[s][0][cf], 0, 0, 0);
        acc[s][0][cf] = __builtin_amdgcn_mfma_f32_16x16x32_bf16(al0, bh[cur][cf], acc[s][0][cf], 0, 0, 0);
        acc[s][1][cf] = __builtin_amdgcn_mfma_f32_16x16x32_bf16(ah1, bh[cur][cf], acc[s][1][cf], 0, 0, 0);
        acc[s][1][cf] = __builtin_amdgcn_mfma_f32_16x16x32_bf16(ah1, bl[cur][cf], acc[s][1][cf], 0, 0, 0);
        acc[s][1][cf] = __builtin_amdgcn_mfma_f32_16x16x32_bf16(al1, bh[cur][cf], acc[s][1][cf], 0, 0, 0);
      }
    }
    __builtin_amdgcn_s_setprio(0);
    if (t < 15) {
      asm volatile("s_waitcnt vmcnt(0)" ::: "memory");  // A(t+1)+B(t+1) landed
      __builtin_amdgcn_s_barrier();
    }
  }

  // ---- epilogue: tanh coupling
  const int frow = lane & 15;
  const int fq = lane >> 4;
#pragma unroll
  for (int rf = 0; rf < 2; ++rf) {
#pragma unroll
    for (int cf = 0; cf < 2; ++cf) {
      const int col = bn + wv * 32 + cf * 16 + frow;
      const float bv = bias[col];
      const size_t fbase = (size_t)(mt0 + rf) * 8192 + (size_t)(col >> 5) * 512 +
                           (size_t)(((col >> 3) & 3) * 128) + (size_t)(col & 7);
#pragma unroll
      for (int j = 0; j < 4; ++j) {
        const float a0 = acc[0][rf][cf][j] + bv;
        const float e = __expf(2.f * a0);
        const float y = 1.f - __fdividef(2.f, e + 1.f);
        const float d = 1.f - y * y;
        const float a1 = acc[1][rf][cf][j];
        const float o1 = d * a1;
        if (LAST) {
          const size_t row = (size_t)(bm + rf * 16 + fq * 4 + j);
          const size_t off = (row << 9) + col;
          if (NS == 5) {
            const float a2 = acc[2][rf][cf][j];
            const float a3 = acc[3][rf][cf][j];
            const float a4 = acc[4][rf][cf][j];
            const float o2 = fmaf(-2.f * y * a1, o1, d * a2);
            const float o3 = d * a3;
            const float o4 = fmaf(-2.f * y * a3, o3, d * a4);
            outf[off] = o2;        // u_tt'' activation
            outf[P + off] = o4;    // u_xx'' activation
          } else {
            outf[off] = y;         // h activation
            outf[P + off] = o1;    // u_t' activation
          }
        } else {
          const size_t off = fbase + (size_t)((fq * 4 + j) << 3);
          st_split(outp + 0 * P, outp + 1 * P, off, y);
          st_split(outp + 2 * P, outp + 3 * P, off, o1);
          if (NS == 5) {
            const float a2 = acc[2][rf][cf][j];
            const float a3 = acc[3][rf][cf][j];
            const float a4 = acc[4][rf][cf][j];
            const float o2 = fmaf(-2.f * y * a1, o1, d * a2);
            const float o3 = d * a3;
            const float o4 = fmaf(-2.f * y * a3, o3, d * a4);
            st_split(outp + 4 * P, outp + 5 * P, off, o2);
            st_split(outp + 6 * P, outp + 7 * P, off, o3);
            st_split(outp + 8 * P, outp + 9 * P, off, o4);
          }
        }
      }
    }
  }
}

// ---------------------------------------------------------------------------
// Final layer (512 -> 1) dots + loss accumulation, f32 row-major inputs.
// ---------------------------------------------------------------------------
__global__ __launch_bounds__(256) void final_int(
    const float* __restrict__ uf, size_t P,
    const float* __restrict__ W4, const float* __restrict__ f,
    const float* __restrict__ c, float* __restrict__ out,
    int rows, float scale)
{
  __shared__ float ls[4];
  int lane = threadIdx.x & 63, w = threadIdx.x >> 6;
  long i = (long)blockIdx.x * 4 + w;
  float val = 0.f;
  if (i < rows) {
    const float* ut = uf + (i << 9) + (lane << 3);
    const float* ux = ut + P;
    float s_t = 0.f, s_x = 0.f;
#pragma unroll
    for (int j = 0; j < 8; ++j) {
      float wv4 = W4[(lane << 3) + j];
      s_t = fmaf(ut[j], wv4, s_t);
      s_x = fmaf(ux[j], wv4, s_x);
    }
#pragma unroll
    for (int off = 32; off; off >>= 1) {
      s_t += __shfl_xor(s_t, off);
      s_x += __shfl_xor(s_x, off);
    }
    if (lane == 0) {
      float c0 = c[0];
      float pred = s_t - c0 * c0 * s_x;
      float r = pred - f[i];
      val = r * r;
    }
  }
  if (lane == 0) ls[w] = val;
  __syncthreads();
  if (threadIdx.x == 0)
    atomicAdd(out + 2, scale * (ls[0] + ls[1] + ls[2] + ls[3]));
}

__global__ __launch_bounds__(256) void final_init(
    const float* __restrict__ uf, size_t P,
    const float* __restrict__ W4, const float* __restrict__ b4,
    const float* __restrict__ g, const float* __restrict__ gd,
    float* __restrict__ out, int rows, float scale)
{
  __shared__ float ls0[4], ls1[4];
  int lane = threadIdx.x & 63, w = threadIdx.x >> 6;
  long i = (long)blockIdx.x * 4 + w;
  float v0 = 0.f, v1 = 0.f;
  if (i < rows) {
    const float* h = uf + (i << 9) + (lane << 3);
    const float* tt = h + P;
    float su = 0.f, stt = 0.f;
#pragma unroll
    for (int j = 0; j < 8; ++j) {
      float wv4 = W4[(lane << 3) + j];
      su = fmaf(h[j], wv4, su);
      stt = fmaf(tt[j], wv4, stt);
    }
#pragma unroll
    for (int off = 32; off; off >>= 1) {
      su += __shfl_xor(su, off);
      stt += __shfl_xor(stt, off);
    }
    if (lane == 0) {
      float r0 = su + b4[0] - g[i];
      float r1 = stt - gd[i];
      v0 = r0 * r0;
      v1 = r1 * r1;
    }
  }
  if (lane == 0) { ls0[w] = v0; ls1[w] = v1; }
  __syncthreads();
  if (threadIdx.x == 0) {
    atomicAdd(out + 0, scale * (ls0[0] + ls0[1] + ls0[2] + ls0[3]));
    atomicAdd(out + 1, scale * (ls1[0] + ls1[1] + ls1[2] + ls1[3]));
  }
}

// ---------------------------------------------------------------------------
extern "C" void kernel_launch(void* const* d_in, const int* in_sizes, int n_in,
                              void* d_out, int out_size, void* d_ws, size_t ws_size,
                              hipStream_t stream)
{
  const float* xt_int  = (const float*)d_in[0];
  const float* f       = (const float*)d_in[1];
  const float* xt_init = (const float*)d_in[2];
  const float* g       = (const float*)d_in[3];
  const float* gd      = (const float*)d_in[4];
  const float* W0 = (const float*)d_in[5];
  const float* b0 = (const float*)d_in[6];
  const float* W1 = (const float*)d_in[7];
  const float* b1 = (const float*)d_in[8];
  const float* W2 = (const float*)d_in[9];
  const float* b2 = (const float*)d_in[10];
  const float* W3 = (const float*)d_in[11];
  const float* b3 = (const float*)d_in[12];
  const float* W4 = (const float*)d_in[13];
  const float* b4 = (const float*)d_in[14];
  const float* c  = (const float*)d_in[15];
  float* out = (float*)d_out;

  hipMemsetAsync(out, 0, 3 * sizeof(float), stream);

  unsigned short* wsp = (unsigned short*)d_ws;
  const size_t WT1 = (size_t)HID * HID;     // one 512x512 plane (elems)
  const size_t wtotal = 6 * WT1;            // 3 layers x {hi,lo}
  unsigned short* Wt = wsp;

  // per-row cost: 2 bf16 buffers x 10 planes x 512 + 1 f32 buffer x 2 planes
  const size_t row_bytes = 2 * 10 * HID * 2 + 2 * HID * 4;  // 24576
  long maxRc = (long)((ws_size - wtotal * 2) / row_bytes);
  // Rc=2048: ping-pong buffers ~21MB each -> ~2.6MB per XCD -> producer ->
  // consumer activation reuse hits the XCD's private L2 (4MB).
  long Rc = 2048;
  while (Rc > maxRc && Rc > 128) Rc >>= 1;
  size_t P = (size_t)Rc * HID;
  unsigned short* bufA = wsp + wtotal;
  unsigned short* bufB = bufA + 10 * P;
  float* fbuf = (float*)(bufB + 10 * P);

  wsplit<<<HID, HID, 0, stream>>>(W1, Wt + 0 * WT1, Wt + 1 * WT1);
  wsplit<<<HID, HID, 0, stream>>>(W2, Wt + 2 * WT1, Wt + 3 * WT1);
  wsplit<<<HID, HID, 0, stream>>>(W3, Wt + 4 * WT1, Wt + 5 * WT1);

  const float sc_f = 0.5f / (float)N_INT;
  const float sc_i = 0.5f / (float)N_INIT;

  // ---- interior pass (5 streams) ----
  for (long i0 = 0; i0 < N_INT; i0 += Rc) {
    long rem = N_INT - i0;
    int rows = (int)(rem < Rc ? rem : Rc);
    layer0_int<<<(rows + 7) / 8, 512, 0, stream>>>(xt_int, i0, rows, W0, b0, bufA, P);
    int nwg = (rows / 32) * 4;
    gemm_mfma<5, false><<<nwg, 256, 0, stream>>>(bufA, Wt + 0 * WT1, Wt + 1 * WT1, b1, bufB, nullptr, P, nwg);
    gemm_mfma<5, false><<<nwg, 256, 0, stream>>>(bufB, Wt + 2 * WT1, Wt + 3 * WT1, b2, bufA, nullptr, P, nwg);
    gemm_mfma<5, true><<<nwg, 256, 0, stream>>>(bufA, Wt + 4 * WT1, Wt + 5 * WT1, b3, nullptr, fbuf, P, nwg);
    final_int<<<(rows + 3) / 4, 256, 0, stream>>>(fbuf, P, W4, f + i0, c, out, rows, sc_f);
  }

  // ---- init pass (2 streams) ----
  for (long i0 = 0; i0 < N_INIT; i0 += Rc) {
    long rem = N_INIT - i0;
    int rows = (int)(rem < Rc ? rem : Rc);
    layer0_init<<<(rows + 7) / 8, 512, 0, stream>>>(xt_init, i0, rows, W0, b0, bufA, P);
    int nwg = (rows / 32) * 4;
    gemm_mfma<2, false><<<nwg, 256, 0, stream>>>(bufA, Wt + 0 * WT1, Wt + 1 * WT1, b1, bufB, nullptr, P, nwg);
    gemm_mfma<2, false><<<nwg, 256, 0, stream>>>(bufB, Wt + 2 * WT1, Wt + 3 * WT1, b2, bufA, nullptr, P, nwg);
    gemm_mfma<2, true><<<nwg, 256, 0, stream>>>(bufA, Wt + 4 * WT1, Wt + 5 * WT1, b3, nullptr, fbuf, P, nwg);
    final_init<<<(rows + 3) / 4, 256, 0, stream>>>(fbuf, P, W4, b4, g + i0, gd + i0, out, rows, sc_i);
  }
}

// Round 10
// 4457.772 us; speedup vs baseline: 2.5581x; 1.5524x over previous
//
#include <hip/hip_runtime.h>
#include <hip/hip_bf16.h>
#include <cstdint>
#include <cstddef>

#define HID 512
#define N_INT 131072
#define N_INIT 32768

typedef __attribute__((ext_vector_type(8))) short short8_t;
typedef __attribute__((ext_vector_type(4))) float floatx4;

__device__ __forceinline__ float bf2f(unsigned short u) {
  return __uint_as_float(((unsigned)u) << 16);
}
__device__ __forceinline__ unsigned short f2bf_rne(float x) {
  unsigned u = __float_as_uint(x);
  unsigned r = u + 0x7FFF + ((u >> 16) & 1);
  return (unsigned short)(r >> 16);
}
__device__ __forceinline__ void st_split(unsigned short* hi, unsigned short* lo,
                                         size_t off, float x) {
  unsigned short h = f2bf_rne(x);
  hi[off] = h;
  lo[off] = f2bf_rne(x - bf2f(h));
}
__device__ __forceinline__ void gl_lds16(const unsigned short* g, unsigned short* l) {
  __builtin_amdgcn_global_load_lds(
      (const __attribute__((address_space(1))) unsigned int*)g,
      (__attribute__((address_space(3))) unsigned int*)l, 16, 0, 0);
}

// fraglet offset for element (row, col) in a [rows][512] matrix stored as
// MFMA-operand fraglets: fraglet (row>>4, col>>5); lane = ((col>>3)&3)*16
// + (row&15); elem = col&7.  One fraglet = 1KB contiguous.
__device__ __forceinline__ size_t foff(int row, int col) {
  return (size_t)(row >> 4) * 8192 + (size_t)(col >> 5) * 512 +
         (size_t)(((col >> 3) & 3) * 128) + (size_t)((row & 15) << 3) +
         (size_t)(col & 7);
}

// ---------------------------------------------------------------------------
// Layer 0 (2 -> 512), closed-form tangents; vectorized: 8 cols/thread, one
// aligned short8 (16B) store per plane. Block = 512 thr = 8 rows x 64 colblk.
// ---------------------------------------------------------------------------
__global__ __launch_bounds__(512) void layer0_int(
    const float* __restrict__ xt, long row0, int rows,
    const float* __restrict__ W0, const float* __restrict__ b0,
    unsigned short* __restrict__ act, size_t P)
{
  const int lr = threadIdx.x >> 6;
  const int cb = threadIdx.x & 63;
  const long i = (long)blockIdx.x * 8 + lr;
  if (i >= rows) return;
  const float x = xt[(row0 + i) * 2 + 0];
  const float t = xt[(row0 + i) * 2 + 1];
  const int j0 = cb << 3;
  const float4 wxa = *(const float4*)(W0 + j0);
  const float4 wxb = *(const float4*)(W0 + j0 + 4);
  const float4 wta = *(const float4*)(W0 + HID + j0);
  const float4 wtb = *(const float4*)(W0 + HID + j0 + 4);
  const float4 ba = *(const float4*)(b0 + j0);
  const float4 bb = *(const float4*)(b0 + j0 + 4);
  const float wxv[8] = {wxa.x, wxa.y, wxa.z, wxa.w, wxb.x, wxb.y, wxb.z, wxb.w};
  const float wtv[8] = {wta.x, wta.y, wta.z, wta.w, wtb.x, wtb.y, wtb.z, wtb.w};
  const float bv[8]  = {ba.x, ba.y, ba.z, ba.w, bb.x, bb.y, bb.z, bb.w};
  short8_t h[5], l[5];
#pragma unroll
  for (int jj = 0; jj < 8; ++jj) {
    const float wx = wxv[jj], wt = wtv[jj];
    const float a = fmaf(x, wx, fmaf(t, wt, bv[jj]));
    const float y = tanhf(a);
    const float d = 1.f - y * y;
    const float vals[5] = {y, d * wt, -2.f * y * d * wt * wt,
                           d * wx, -2.f * y * d * wx * wx};
#pragma unroll
    for (int p = 0; p < 5; ++p) {
      const unsigned short hv = f2bf_rne(vals[p]);
      h[p][jj] = (short)hv;
      l[p][jj] = (short)f2bf_rne(vals[p] - bf2f(hv));
    }
  }
  const size_t base = foff((int)i, j0);
#pragma unroll
  for (int p = 0; p < 5; ++p) {
    *(short8_t*)(act + (size_t)(2 * p) * P + base) = h[p];
    *(short8_t*)(act + (size_t)(2 * p + 1) * P + base) = l[p];
  }
}

__global__ __launch_bounds__(512) void layer0_init(
    const float* __restrict__ xt, long row0, int rows,
    const float* __restrict__ W0, const float* __restrict__ b0,
    unsigned short* __restrict__ act, size_t P)
{
  const int lr = threadIdx.x >> 6;
  const int cb = threadIdx.x & 63;
  const long i = (long)blockIdx.x * 8 + lr;
  if (i >= rows) return;
  const float x = xt[(row0 + i) * 2 + 0];
  const float t = xt[(row0 + i) * 2 + 1];
  const int j0 = cb << 3;
  const float4 wxa = *(const float4*)(W0 + j0);
  const float4 wxb = *(const float4*)(W0 + j0 + 4);
  const float4 wta = *(const float4*)(W0 + HID + j0);
  const float4 wtb = *(const float4*)(W0 + HID + j0 + 4);
  const float4 ba = *(const float4*)(b0 + j0);
  const float4 bb = *(const float4*)(b0 + j0 + 4);
  const float wxv[8] = {wxa.x, wxa.y, wxa.z, wxa.w, wxb.x, wxb.y, wxb.z, wxb.w};
  const float wtv[8] = {wta.x, wta.y, wta.z, wta.w, wtb.x, wtb.y, wtb.z, wtb.w};
  const float bv[8]  = {ba.x, ba.y, ba.z, ba.w, bb.x, bb.y, bb.z, bb.w};
  short8_t h[2], l[2];
#pragma unroll
  for (int jj = 0; jj < 8; ++jj) {
    const float wx = wxv[jj], wt = wtv[jj];
    const float a = fmaf(x, wx, fmaf(t, wt, bv[jj]));
    const float y = tanhf(a);
    const float d = 1.f - y * y;
    const float vals[2] = {y, d * wt};
#pragma unroll
    for (int p = 0; p < 2; ++p) {
      const unsigned short hv = f2bf_rne(vals[p]);
      h[p][jj] = (short)hv;
      l[p][jj] = (short)f2bf_rne(vals[p] - bf2f(hv));
    }
  }
  const size_t base = foff((int)i, j0);
#pragma unroll
  for (int p = 0; p < 2; ++p) {
    *(short8_t*)(act + (size_t)(2 * p) * P + base) = h[p];
    *(short8_t*)(act + (size_t)(2 * p + 1) * P + base) = l[p];
  }
}

// ---------------------------------------------------------------------------
// W split + pack into B-fraglet layout (n -> fraglet row role):
//   fraglet (n>>4, k>>5); lane = ((k>>3)&3)*16 + (n&15); elem = k&7.
// ---------------------------------------------------------------------------
__global__ __launch_bounds__(512) void wsplit(
    const float* __restrict__ W,
    unsigned short* __restrict__ WfH, unsigned short* __restrict__ WfL)
{
  int n = blockIdx.x;
  int k = threadIdx.x;
  float w = W[(size_t)k * HID + n];
  size_t o = ((((size_t)(n >> 4) * 16 + (k >> 5)) * 64
               + ((k >> 3) & 3) * 16 + (n & 15)) << 3) + (k & 7);
  st_split(WfH, WfL, o, w);
}

// ---------------------------------------------------------------------------
// Fused NS-stream split-bf16 MFMA GEMM, depth-2 counted-vmcnt pipeline.
// 256 thr = 4 waves (1m x 4n); block tile 32x128; wave tile 32x32 per stream.
// A: 3 LDS fraglet buffers (global_load_lds, linear both sides); B: 3-slot
// register buffer. Per iter t: vmcnt(BATCH) waits ONLY batch t (batch t+1
// stays in flight across the barrier) -> barrier -> issue batch t+2 ->
// MFMA burst. Loads get two full bursts (~4700cyc) of cover; the barrier is
// never preceded by a dependent drain (T3+T4 pattern, never vmcnt(0) mid-loop).
// C = Ah@Wh + Ah@Wl + Al@Wh (fp32 accum) per stream, W shared across streams.
// ---------------------------------------------------------------------------
template <int NS, bool LAST>
__global__ __launch_bounds__(256, 2) void gemm_mfma(
    const unsigned short* __restrict__ inp,   // 2*NS fraglet planes of P elems
    const unsigned short* __restrict__ WfH,   // fraglet-packed 512x512
    const unsigned short* __restrict__ WfL,
    const float* __restrict__ bias,
    unsigned short* __restrict__ outp,        // 2*NS fraglet planes (!LAST)
    float* __restrict__ outf,                 // 2 f32 planes (LAST)
    size_t P, int nwg)
{
  __shared__ unsigned short Asm[3][NS * 4 * 512];  // 3-deep fraglet buffers

  const int bid = blockIdx.x;
  // XCD-grouped order (nwg multiple of 8): the 4 n-blocks of an m-panel are
  // consecutive logical ids -> same XCD -> A panel re-reads hit that L2/L3.
  const int o = (bid & 7) * (nwg >> 3) + (bid >> 3);
  const long bm = (long)(o >> 2) << 5;
  const int bn = (o & 3) << 7;

  const int lane = threadIdx.x & 63;
  const int wv = threadIdx.x >> 6;   // 0..3 = n-quarter

  floatx4 acc[NS][2][2];             // [stream][rf(m16)][cf(n16)]
#pragma unroll
  for (int s = 0; s < NS; ++s)
#pragma unroll
    for (int rf = 0; rf < 2; ++rf)
#pragma unroll
      for (int cf = 0; cf < 2; ++cf)
#pragma unroll
        for (int e = 0; e < 4; ++e) acc[s][rf][cf][e] = 0.f;

  const int mt0 = (int)(bm >> 4);

  // ---- A staging: NS*4 fraglets per k-step, NS per wave.
  // fraglet id f = s*4 + mt*2 + p  (mt: m-tile within block, p: hi/lo)
  const unsigned short* asrc[NS];
  unsigned adst[NS];
#pragma unroll
  for (int u = 0; u < NS; ++u) {
    const int f = wv * NS + u;
    const int s = f >> 2, mtl = (f >> 1) & 1, p = f & 1;
    asrc[u] = inp + (size_t)(2 * s + p) * P + (size_t)(mt0 + mtl) * 8192 + (lane << 3);
    adst[u] = (unsigned)f * 512;
  }

  // ---- B fraglet pointers (16B/lane coalesced); this wave's 2 n-tiles
  const int bnt = (bn >> 4) + wv * 2;
  const unsigned short* bbh = WfH + ((size_t)bnt << 13) + (lane << 3);
  const unsigned short* bbl = WfL + ((size_t)bnt << 13) + (lane << 3);

  short8_t bh[3][2], bl[3][2];  // [k mod 3][cf]

  // ---- prologue: issue batches 0 and 1 (batch = NS gl_lds + 4 B loads)
#pragma unroll
  for (int b = 0; b < 2; ++b) {
#pragma unroll
    for (int u = 0; u < NS; ++u)
      gl_lds16(asrc[u] + (b << 9), &Asm[b][adst[u]]);
#pragma unroll
    for (int cf = 0; cf < 2; ++cf) {
      bh[b][cf] = *(const short8_t*)(bbh + ((size_t)cf << 13) + (b << 9));
      bl[b][cf] = *(const short8_t*)(bbl + ((size_t)cf << 13) + (b << 9));
    }
  }

#pragma unroll
  for (int t = 0; t < 16; ++t) {
    const int cur = t % 3;
    // wait for batch t only (batch t+1 remains in flight across the barrier)
    if (t < 15) {
      if (NS == 5) asm volatile("s_waitcnt vmcnt(9)" ::: "memory");
      else         asm volatile("s_waitcnt vmcnt(6)" ::: "memory");
    } else {
      asm volatile("s_waitcnt vmcnt(0)" ::: "memory");
    }
    __builtin_amdgcn_s_barrier();
    if (t < 14) {
      // issue batch t+2 into buffer freed by MFMA(t-1) (barrier-confirmed)
      const int nb = (t + 2) % 3;
#pragma unroll
      for (int u = 0; u < NS; ++u)
        gl_lds16(asrc[u] + ((t + 2) << 9), &Asm[nb][adst[u]]);
#pragma unroll
      for (int cf = 0; cf < 2; ++cf) {
        bh[nb][cf] = *(const short8_t*)(bbh + ((size_t)cf << 13) + ((t + 2) << 9));
        bl[nb][cf] = *(const short8_t*)(bbl + ((size_t)cf << 13) + ((t + 2) << 9));
      }
    }
    // MFMA burst on buffer cur (A from LDS, B from regs; batch t confirmed)
    __builtin_amdgcn_s_setprio(1);
#pragma unroll
    for (int s = 0; s < NS; ++s) {
      const unsigned short* As = &Asm[cur][(unsigned)s * 2048 + (lane << 3)];
      const short8_t ah0 = *(const short8_t*)(As);
      const short8_t al0 = *(const short8_t*)(As + 512);
      const short8_t ah1 = *(const short8_t*)(As + 1024);
      const short8_t al1 = *(const short8_t*)(As + 1536);
#pragma unroll
      for (int cf = 0; cf < 2; ++cf) {
        acc[s][0][cf] = __builtin_amdgcn_mfma_f32_16x16x32_bf16(ah0, bh[cur][cf], acc[s][0][cf], 0, 0, 0);
        acc[s][0][cf] = __builtin_amdgcn_mfma_f32_16x16x32_bf16(ah0, bl[cur][cf], acc[s][0][cf], 0, 0, 0);
        acc[s][0][cf] = __builtin_amdgcn_mfma_f32_16x16x32_bf16(al0, bh[cur][cf], acc[s][0][cf], 0, 0, 0);
        acc[s][1][cf] = __builtin_amdgcn_mfma_f32_16x16x32_bf16(ah1, bh[cur][cf], acc[s][1][cf], 0, 0, 0);
        acc[s][1][cf] = __builtin_amdgcn_mfma_f32_16x16x32_bf16(ah1, bl[cur][cf], acc[s][1][cf], 0, 0, 0);
        acc[s][1][cf] = __builtin_amdgcn_mfma_f32_16x16x32_bf16(al1, bh[cur][cf], acc[s][1][cf], 0, 0, 0);
      }
    }
    __builtin_amdgcn_s_setprio(0);
  }

  // ---- epilogue: tanh coupling
  const int frow = lane & 15;
  const int fq = lane >> 4;
#pragma unroll
  for (int rf = 0; rf < 2; ++rf) {
#pragma unroll
    for (int cf = 0; cf < 2; ++cf) {
      const int col = bn + wv * 32 + cf * 16 + frow;
      const float bv = bias[col];
      const size_t fbase = (size_t)(mt0 + rf) * 8192 + (size_t)(col >> 5) * 512 +
                           (size_t)(((col >> 3) & 3) * 128) + (size_t)(col & 7);
#pragma unroll
      for (int j = 0; j < 4; ++j) {
        const float a0 = acc[0][rf][cf][j] + bv;
        const float e = __expf(2.f * a0);
        const float y = 1.f - __fdividef(2.f, e + 1.f);
        const float d = 1.f - y * y;
        const float a1 = acc[1][rf][cf][j];
        const float o1 = d * a1;
        if (LAST) {
          const size_t row = (size_t)(bm + rf * 16 + fq * 4 + j);
          const size_t off = (row << 9) + col;
          if (NS == 5) {
            const float a2 = acc[2][rf][cf][j];
            const float a3 = acc[3][rf][cf][j];
            const float a4 = acc[4][rf][cf][j];
            const float o2 = fmaf(-2.f * y * a1, o1, d * a2);
            const float o3 = d * a3;
            const float o4 = fmaf(-2.f * y * a3, o3, d * a4);
            outf[off] = o2;        // u_tt'' activation
            outf[P + off] = o4;    // u_xx'' activation
          } else {
            outf[off] = y;         // h activation
            outf[P + off] = o1;    // u_t' activation
          }
        } else {
          const size_t off = fbase + (size_t)((fq * 4 + j) << 3);
          st_split(outp + 0 * P, outp + 1 * P, off, y);
          st_split(outp + 2 * P, outp + 3 * P, off, o1);
          if (NS == 5) {
            const float a2 = acc[2][rf][cf][j];
            const float a3 = acc[3][rf][cf][j];
            const float a4 = acc[4][rf][cf][j];
            const float o2 = fmaf(-2.f * y * a1, o1, d * a2);
            const float o3 = d * a3;
            const float o4 = fmaf(-2.f * y * a3, o3, d * a4);
            st_split(outp + 4 * P, outp + 5 * P, off, o2);
            st_split(outp + 6 * P, outp + 7 * P, off, o3);
            st_split(outp + 8 * P, outp + 9 * P, off, o4);
          }
        }
      }
    }
  }
}

// ---------------------------------------------------------------------------
// Final layer (512 -> 1) dots + loss accumulation, f32 row-major inputs.
// ---------------------------------------------------------------------------
__global__ __launch_bounds__(256) void final_int(
    const float* __restrict__ uf, size_t P,
    const float* __restrict__ W4, const float* __restrict__ f,
    const float* __restrict__ c, float* __restrict__ out,
    int rows, float scale)
{
  __shared__ float ls[4];
  int lane = threadIdx.x & 63, w = threadIdx.x >> 6;
  long i = (long)blockIdx.x * 4 + w;
  float val = 0.f;
  if (i < rows) {
    const float* ut = uf + (i << 9) + (lane << 3);
    const float* ux = ut + P;
    float s_t = 0.f, s_x = 0.f;
#pragma unroll
    for (int j = 0; j < 8; ++j) {
      float wv4 = W4[(lane << 3) + j];
      s_t = fmaf(ut[j], wv4, s_t);
      s_x = fmaf(ux[j], wv4, s_x);
    }
#pragma unroll
    for (int off = 32; off; off >>= 1) {
      s_t += __shfl_xor(s_t, off);
      s_x += __shfl_xor(s_x, off);
    }
    if (lane == 0) {
      float c0 = c[0];
      float pred = s_t - c0 * c0 * s_x;
      float r = pred - f[i];
      val = r * r;
    }
  }
  if (lane == 0) ls[w] = val;
  __syncthreads();
  if (threadIdx.x == 0)
    atomicAdd(out + 2, scale * (ls[0] + ls[1] + ls[2] + ls[3]));
}

__global__ __launch_bounds__(256) void final_init(
    const float* __restrict__ uf, size_t P,
    const float* __restrict__ W4, const float* __restrict__ b4,
    const float* __restrict__ g, const float* __restrict__ gd,
    float* __restrict__ out, int rows, float scale)
{
  __shared__ float ls0[4], ls1[4];
  int lane = threadIdx.x & 63, w = threadIdx.x >> 6;
  long i = (long)blockIdx.x * 4 + w;
  float v0 = 0.f, v1 = 0.f;
  if (i < rows) {
    const float* h = uf + (i << 9) + (lane << 3);
    const float* tt = h + P;
    float su = 0.f, stt = 0.f;
#pragma unroll
    for (int j = 0; j < 8; ++j) {
      float wv4 = W4[(lane << 3) + j];
      su = fmaf(h[j], wv4, su);
      stt = fmaf(tt[j], wv4, stt);
    }
#pragma unroll
    for (int off = 32; off; off >>= 1) {
      su += __shfl_xor(su, off);
      stt += __shfl_xor(stt, off);
    }
    if (lane == 0) {
      float r0 = su + b4[0] - g[i];
      float r1 = stt - gd[i];
      v0 = r0 * r0;
      v1 = r1 * r1;
    }
  }
  if (lane == 0) { ls0[w] = v0; ls1[w] = v1; }
  __syncthreads();
  if (threadIdx.x == 0) {
    atomicAdd(out + 0, scale * (ls0[0] + ls0[1] + ls0[2] + ls0[3]));
    atomicAdd(out + 1, scale * (ls1[0] + ls1[1] + ls1[2] + ls1[3]));
  }
}

// ---------------------------------------------------------------------------
extern "C" void kernel_launch(void* const* d_in, const int* in_sizes, int n_in,
                              void* d_out, int out_size, void* d_ws, size_t ws_size,
                              hipStream_t stream)
{
  const float* xt_int  = (const float*)d_in[0];
  const float* f       = (const float*)d_in[1];
  const float* xt_init = (const float*)d_in[2];
  const float* g       = (const float*)d_in[3];
  const float* gd      = (const float*)d_in[4];
  const float* W0 = (const float*)d_in[5];
  const float* b0 = (const float*)d_in[6];
  const float* W1 = (const float*)d_in[7];
  const float* b1 = (const float*)d_in[8];
  const float* W2 = (const float*)d_in[9];
  const float* b2 = (const float*)d_in[10];
  const float* W3 = (const float*)d_in[11];
  const float* b3 = (const float*)d_in[12];
  const float* W4 = (const float*)d_in[13];
  const float* b4 = (const float*)d_in[14];
  const float* c  = (const float*)d_in[15];
  float* out = (float*)d_out;

  hipMemsetAsync(out, 0, 3 * sizeof(float), stream);

  unsigned short* wsp = (unsigned short*)d_ws;
  const size_t WT1 = (size_t)HID * HID;     // one 512x512 plane (elems)
  const size_t wtotal = 6 * WT1;            // 3 layers x {hi,lo}
  unsigned short* Wt = wsp;

  // per-row cost: 2 bf16 buffers x 10 planes x 512 + 1 f32 buffer x 2 planes
  const size_t row_bytes = 2 * 10 * HID * 2 + 2 * HID * 4;  // 24576
  long maxRc = (long)((ws_size - wtotal * 2) / row_bytes);
  long Rc = 128;
  while (Rc * 2 <= maxRc && Rc < 8192) Rc <<= 1;
  size_t P = (size_t)Rc * HID;
  unsigned short* bufA = wsp + wtotal;
  unsigned short* bufB = bufA + 10 * P;
  float* fbuf = (float*)(bufB + 10 * P);

  wsplit<<<HID, HID, 0, stream>>>(W1, Wt + 0 * WT1, Wt + 1 * WT1);
  wsplit<<<HID, HID, 0, stream>>>(W2, Wt + 2 * WT1, Wt + 3 * WT1);
  wsplit<<<HID, HID, 0, stream>>>(W3, Wt + 4 * WT1, Wt + 5 * WT1);

  const float sc_f = 0.5f / (float)N_INT;
  const float sc_i = 0.5f / (float)N_INIT;

  // ---- interior pass (5 streams) ----
  for (long i0 = 0; i0 < N_INT; i0 += Rc) {
    long rem = N_INT - i0;
    int rows = (int)(rem < Rc ? rem : Rc);
    layer0_int<<<(rows + 7) / 8, 512, 0, stream>>>(xt_int, i0, rows, W0, b0, bufA, P);
    int nwg = (rows / 32) * 4;
    gemm_mfma<5, false><<<nwg, 256, 0, stream>>>(bufA, Wt + 0 * WT1, Wt + 1 * WT1, b1, bufB, nullptr, P, nwg);
    gemm_mfma<5, false><<<nwg, 256, 0, stream>>>(bufB, Wt + 2 * WT1, Wt + 3 * WT1, b2, bufA, nullptr, P, nwg);
    gemm_mfma<5, true><<<nwg, 256, 0, stream>>>(bufA, Wt + 4 * WT1, Wt + 5 * WT1, b3, nullptr, fbuf, P, nwg);
    final_int<<<(rows + 3) / 4, 256, 0, stream>>>(fbuf, P, W4, f + i0, c, out, rows, sc_f);
  }

  // ---- init pass (2 streams) ----
  for (long i0 = 0; i0 < N_INIT; i0 += Rc) {
    long rem = N_INIT - i0;
    int rows = (int)(rem < Rc ? rem : Rc);
    layer0_init<<<(rows + 7) / 8, 512, 0, stream>>>(xt_init, i0, rows, W0, b0, bufA, P);
    int nwg = (rows / 32) * 4;
    gemm_mfma<2, false><<<nwg, 256, 0, stream>>>(bufA, Wt + 0 * WT1, Wt + 1 * WT1, b1, bufB, nullptr, P, nwg);
    gemm_mfma<2, false><<<nwg, 256, 0, stream>>>(bufB, Wt + 2 * WT1, Wt + 3 * WT1, b2, bufA, nullptr, P, nwg);
    gemm_mfma<2, true><<<nwg, 256, 0, stream>>>(bufA, Wt + 4 * WT1, Wt + 5 * WT1, b3, nullptr, fbuf, P, nwg);
    final_init<<<(rows + 3) / 4, 256, 0, stream>>>(fbuf, P, W4, b4, g + i0, gd + i0, out, rows, sc_i);
  }
}

// Round 11
// 2553.338 us; speedup vs baseline: 4.4661x; 1.7459x over previous
//
#include <hip/hip_runtime.h>
#include <hip/hip_bf16.h>
#include <cstdint>
#include <cstddef>

#define HID 512
#define N_INT 131072
#define N_INIT 32768
#define WT1 ((size_t)HID * HID)

typedef __attribute__((ext_vector_type(8))) short short8_t;
typedef __attribute__((ext_vector_type(4))) float floatx4;

__device__ __forceinline__ float bf2f(unsigned short u) {
  return __uint_as_float(((unsigned)u) << 16);
}
__device__ __forceinline__ unsigned short f2bf_rne(float x) {
  unsigned u = __float_as_uint(x);
  unsigned r = u + 0x7FFF + ((u >> 16) & 1);
  return (unsigned short)(r >> 16);
}
__device__ __forceinline__ void st_split(unsigned short* hi, unsigned short* lo,
                                         size_t off, float x) {
  unsigned short h = f2bf_rne(x);
  hi[off] = h;
  lo[off] = f2bf_rne(x - bf2f(h));
}

// LDS activation plane layout: [16 rows][1024 ushorts: hi 0..511 | lo 512..1023],
// 16B slot index XOR-swizzled with (row&7) -> A-fragment reads are 2 lanes/bank.
__device__ __forceinline__ int aoff(int row, int uscol) {
  return (row << 10) + ((((uscol >> 3) ^ (row & 7)) << 3) | (uscol & 7));
}
__device__ __forceinline__ void lds_split(unsigned short* plane, int row, int col, float v) {
  unsigned short h = f2bf_rne(v);
  plane[aoff(row, col)] = h;
  plane[aoff(row, 512 + col)] = f2bf_rne(v - bf2f(h));
}

// ---------------------------------------------------------------------------
// W split + pack into B-fraglet layout (same as prior verified rounds):
//   fraglet (n>>4, k>>5); lane = ((k>>3)&3)*16 + (n&15); elem = k&7.
// ---------------------------------------------------------------------------
__global__ __launch_bounds__(512) void wsplit(
    const float* __restrict__ W,
    unsigned short* __restrict__ WfH, unsigned short* __restrict__ WfL)
{
  int n = blockIdx.x;
  int k = threadIdx.x;
  float w = W[(size_t)k * HID + n];
  size_t o = ((((size_t)(n >> 4) * 16 + (k >> 5)) * 64
               + ((k >> 3) & 3) * 16 + (n & 15)) << 3) + (k & 7);
  st_split(WfH, WfL, o, w);
}

// ---------------------------------------------------------------------------
// Fully fused MLP pass: layer0 (closed form) -> 3 hidden GEMM layers through
// LDS -> final 512->1 dot + loss. Block = 16 rows x 512 cols, 512 thr (8
// waves, each owns a 64-col slice). Activations never touch HBM.
// NS=5: interior (h, u_t', u_tt'', u_x', u_xx'') -> loss_f (out[2])
// NS=2: init (h, u_t') -> loss_init (out[0]), loss_init_deriv (out[1])
// Split-bf16 GEMM: C = Ah@Wh + Ah@Wl + Al@Wh, fp32 accum (order as rounds 2-10).
// ---------------------------------------------------------------------------
template <int NS>
__global__ __launch_bounds__(512) void fused_mlp(
    const float* __restrict__ xt,
    const float* __restrict__ W0, const float* __restrict__ b0,
    const unsigned short* __restrict__ Wf,   // 6 planes: L1H,L1L,L2H,L2L,L3H,L3L
    const float* __restrict__ b1, const float* __restrict__ b2,
    const float* __restrict__ b3,
    const float* __restrict__ W4, const float* __restrict__ b4,
    const float* __restrict__ cc,            // c (interior), unused for init
    const float* __restrict__ t0,            // f (interior) or g (init)
    const float* __restrict__ t1,            // unused or gd (init)
    float* __restrict__ out, float scale)
{
  __shared__ unsigned short Ald[NS][16][1024];  // NS=5 -> 160 KiB, NS=2 -> 64 KiB

  const int tid = threadIdx.x;
  const long rowbase = (long)blockIdx.x * 16;

  // ---- layer 0: closed-form tangents straight into LDS ----
  {
    const int row = tid & 15;
    const int cg = tid >> 4;  // 0..31, 16 cols each
    const long gr = rowbase + row;
    const float x = xt[gr * 2 + 0];
    const float tv = xt[gr * 2 + 1];
#pragma unroll
    for (int sc = 0; sc < 2; ++sc) {
      const int j0 = cg * 16 + sc * 8;
      short8_t h[NS], l[NS];
#pragma unroll
      for (int jj = 0; jj < 8; ++jj) {
        const float wx = W0[j0 + jj];
        const float wt = W0[HID + j0 + jj];
        const float a = fmaf(x, wx, fmaf(tv, wt, b0[j0 + jj]));
        const float y = tanhf(a);
        const float d = 1.f - y * y;
        const float vals[5] = {y, d * wt, -2.f * y * d * wt * wt,
                               d * wx, -2.f * y * d * wx * wx};
#pragma unroll
        for (int p = 0; p < NS; ++p) {
          const unsigned short hv = f2bf_rne(vals[p]);
          h[p][jj] = (short)hv;
          l[p][jj] = (short)f2bf_rne(vals[p] - bf2f(hv));
        }
      }
#pragma unroll
      for (int p = 0; p < NS; ++p) {
        *(short8_t*)&Ald[p][0][aoff(row, j0)] = h[p];
        *(short8_t*)&Ald[p][0][aoff(row, 512 + j0)] = l[p];
      }
    }
  }
  __syncthreads();

  // ---- 3 hidden GEMM layers ----
  const int lane = tid & 63;
  const int wv = tid >> 6;        // 0..7: 64-col slice
  const int row = lane & 15;      // A row / C col-within-16
  const int kq = lane >> 4;       // k-quarter
  const int rx = row & 7;
  const int rbase = row << 10;

  for (int L = 0; L < 3; ++L) {
    const unsigned short* __restrict__ WH = Wf + (size_t)L * 2 * WT1;
    const unsigned short* __restrict__ WL2 = WH + WT1;

    floatx4 acc[NS][4];
#pragma unroll
    for (int s = 0; s < NS; ++s)
#pragma unroll
      for (int cf = 0; cf < 4; ++cf)
#pragma unroll
        for (int e = 0; e < 4; ++e) acc[s][cf][e] = 0.f;

#pragma unroll 4
    for (int t = 0; t < 16; ++t) {
      short8_t ah[NS], al[NS], bhv[4], blv[4];
#pragma unroll
      for (int s = 0; s < NS; ++s) {
        ah[s] = *(const short8_t*)&Ald[s][0][rbase + ((((t << 2) + kq) ^ rx) << 3)];
        al[s] = *(const short8_t*)&Ald[s][0][rbase + (((64 + (t << 2) + kq) ^ rx) << 3)];
      }
#pragma unroll
      for (int cf = 0; cf < 4; ++cf) {
        const size_t bo = (((size_t)((wv * 4 + cf) * 16 + t)) << 9) + (lane << 3);
        bhv[cf] = *(const short8_t*)(WH + bo);
        blv[cf] = *(const short8_t*)(WL2 + bo);
      }
#pragma unroll
      for (int s = 0; s < NS; ++s)
#pragma unroll
        for (int cf = 0; cf < 4; ++cf) {
          acc[s][cf] = __builtin_amdgcn_mfma_f32_16x16x32_bf16(ah[s], bhv[cf], acc[s][cf], 0, 0, 0);
          acc[s][cf] = __builtin_amdgcn_mfma_f32_16x16x32_bf16(ah[s], blv[cf], acc[s][cf], 0, 0, 0);
          acc[s][cf] = __builtin_amdgcn_mfma_f32_16x16x32_bf16(al[s], bhv[cf], acc[s][cf], 0, 0, 0);
        }
    }
    __syncthreads();  // all waves done reading this layer's activations

    if (L < 2) {
      // ---- coupling epilogue -> write next layer's activations to LDS ----
      const float* __restrict__ bias = (L == 0) ? b1 : b2;
#pragma unroll
      for (int cf = 0; cf < 4; ++cf) {
        const int col = (wv << 6) + (cf << 4) + row;
        const float bv = bias[col];
#pragma unroll
        for (int j = 0; j < 4; ++j) {
          const int ro = (kq << 2) + j;
          const float a0 = acc[0][cf][j] + bv;
          const float e = __expf(2.f * a0);
          const float y = 1.f - __fdividef(2.f, e + 1.f);
          const float d = 1.f - y * y;
          const float a1 = acc[1][cf][j];
          const float o1 = d * a1;
          lds_split(&Ald[0][0][0], ro, col, y);
          lds_split(&Ald[1][0][0], ro, col, o1);
          if (NS == 5) {
            const float a2 = acc[2][cf][j];
            const float a3 = acc[3][cf][j];
            const float a4 = acc[4][cf][j];
            const float o2 = fmaf(-2.f * y * a1, o1, d * a2);
            const float o3 = d * a3;
            const float o4 = fmaf(-2.f * y * a3, o3, d * a4);
            lds_split(&Ald[2][0][0], ro, col, o2);
            lds_split(&Ald[3][0][0], ro, col, o3);
            lds_split(&Ald[4][0][0], ro, col, o4);
          }
        }
      }
      __syncthreads();
    } else {
      // ---- final layer: coupling + 512->1 dot + loss ----
      float p0[4] = {0.f, 0.f, 0.f, 0.f};
      float p1[4] = {0.f, 0.f, 0.f, 0.f};
#pragma unroll
      for (int cf = 0; cf < 4; ++cf) {
        const int col = (wv << 6) + (cf << 4) + row;
        const float bv = b3[col];
        const float w4 = W4[col];
#pragma unroll
        for (int j = 0; j < 4; ++j) {
          const float a0 = acc[0][cf][j] + bv;
          const float e = __expf(2.f * a0);
          const float y = 1.f - __fdividef(2.f, e + 1.f);
          const float d = 1.f - y * y;
          const float a1 = acc[1][cf][j];
          const float o1 = d * a1;
          if (NS == 5) {
            const float a2 = acc[2][cf][j];
            const float a3 = acc[3][cf][j];
            const float a4 = acc[4][cf][j];
            const float o2 = fmaf(-2.f * y * a1, o1, d * a2);
            const float o3 = d * a3;
            const float o4 = fmaf(-2.f * y * a3, o3, d * a4);
            p0[j] = fmaf(o2, w4, p0[j]);   // u_tt partial
            p1[j] = fmaf(o4, w4, p1[j]);   // u_xx partial
          } else {
            p0[j] = fmaf(y, w4, p0[j]);    // u partial
            p1[j] = fmaf(o1, w4, p1[j]);   // u_t partial
          }
        }
      }
      // reduce across the 16 lanes sharing a row-group (cols of this wave)
#pragma unroll
      for (int off = 1; off < 16; off <<= 1)
#pragma unroll
        for (int j = 0; j < 4; ++j) {
          p0[j] += __shfl_xor(p0[j], off);
          p1[j] += __shfl_xor(p1[j], off);
        }
      // cross-wave reduce via LDS scratch (activations no longer needed)
      float* scr = (float*)&Ald[0][0][0];  // [2][8][16]
      if (row == 0) {
#pragma unroll
        for (int j = 0; j < 4; ++j) {
          scr[(wv << 4) + (kq << 2) + j] = p0[j];
          scr[128 + (wv << 4) + (kq << 2) + j] = p1[j];
        }
      }
      __syncthreads();
      if (tid < 16) {
        float s0 = 0.f, s1 = 0.f;
#pragma unroll
        for (int w = 0; w < 8; ++w) {
          s0 += scr[(w << 4) + tid];
          s1 += scr[128 + (w << 4) + tid];
        }
        if (NS == 5) {
          const float c0 = cc[0];
          const float pred = s0 - c0 * c0 * s1;
          const float r = pred - t0[rowbase + tid];
          float v = r * r;
#pragma unroll
          for (int off = 1; off < 16; off <<= 1) v += __shfl_xor(v, off);
          if (tid == 0) atomicAdd(out + 2, scale * v);
        } else {
          const float r0 = s0 + b4[0] - t0[rowbase + tid];
          const float r1 = s1 - t1[rowbase + tid];
          float v0 = r0 * r0, v1 = r1 * r1;
#pragma unroll
          for (int off = 1; off < 16; off <<= 1) {
            v0 += __shfl_xor(v0, off);
            v1 += __shfl_xor(v1, off);
          }
          if (tid == 0) {
            atomicAdd(out + 0, scale * v0);
            atomicAdd(out + 1, scale * v1);
          }
        }
      }
    }
  }
}

// ---------------------------------------------------------------------------
extern "C" void kernel_launch(void* const* d_in, const int* in_sizes, int n_in,
                              void* d_out, int out_size, void* d_ws, size_t ws_size,
                              hipStream_t stream)
{
  const float* xt_int  = (const float*)d_in[0];
  const float* f       = (const float*)d_in[1];
  const float* xt_init = (const float*)d_in[2];
  const float* g       = (const float*)d_in[3];
  const float* gd      = (const float*)d_in[4];
  const float* W0 = (const float*)d_in[5];
  const float* b0 = (const float*)d_in[6];
  const float* W1 = (const float*)d_in[7];
  const float* b1 = (const float*)d_in[8];
  const float* W2 = (const float*)d_in[9];
  const float* b2 = (const float*)d_in[10];
  const float* W3 = (const float*)d_in[11];
  const float* b3 = (const float*)d_in[12];
  const float* W4 = (const float*)d_in[13];
  const float* b4 = (const float*)d_in[14];
  const float* c  = (const float*)d_in[15];
  float* out = (float*)d_out;

  hipMemsetAsync(out, 0, 3 * sizeof(float), stream);

  unsigned short* Wt = (unsigned short*)d_ws;  // 6 planes = 3 MiB of ws

  wsplit<<<HID, HID, 0, stream>>>(W1, Wt + 0 * WT1, Wt + 1 * WT1);
  wsplit<<<HID, HID, 0, stream>>>(W2, Wt + 2 * WT1, Wt + 3 * WT1);
  wsplit<<<HID, HID, 0, stream>>>(W3, Wt + 4 * WT1, Wt + 5 * WT1);

  const float sc_f = 0.5f / (float)N_INT;
  const float sc_i = 0.5f / (float)N_INIT;

  fused_mlp<5><<<N_INT / 16, 512, 0, stream>>>(
      xt_int, W0, b0, Wt, b1, b2, b3, W4, b4, c, f, nullptr, out, sc_f);
  fused_mlp<2><<<N_INIT / 16, 512, 0, stream>>>(
      xt_init, W0, b0, Wt, b1, b2, b3, W4, b4, nullptr, g, gd, out, sc_i);
}